// Round 7
// baseline (516.113 us; speedup 1.0000x reference)
//
#include <hip/hip_runtime.h>

#define B 4
#define N 2048
#define MAXIT 11       // body runs for it = 0..10
#define TOL 1e-4f
#define NBLK 128       // 4 batches x 32 query-chunks of 64
#define NT 256

// ---------------- workspace layout (max offset 164352 < r4-proven 229888) ---
// [0,      98304)   float temp[B][N][3]  (accessed as packed u64 float-pairs)
// [98304, 163840)   u64 nn[B][N]         (packed (d2bits<<32)|idx, no init needed)
// [163840, +4)      unsigned cnt         (memset 0 pre-launch)
// [163904, +4)      int done             (memset 0 pre-launch)

// -------- coherent (MALL-backed) access helpers — r4-proven --------
__device__ __forceinline__ float cohldf(const float* p) {
    return __hip_atomic_load(p, __ATOMIC_RELAXED, __HIP_MEMORY_SCOPE_AGENT);
}
__device__ __forceinline__ unsigned long long cohld64(const unsigned long long* p) {
    return __hip_atomic_load(p, __ATOMIC_RELAXED, __HIP_MEMORY_SCOPE_AGENT);
}
__device__ __forceinline__ void cohst64(unsigned long long* p, unsigned long long v) {
    __hip_atomic_store(p, v, __ATOMIC_RELAXED, __HIP_MEMORY_SCOPE_AGENT);
}
__device__ __forceinline__ unsigned long long umin64(unsigned long long a, unsigned long long b) {
    return a < b ? a : b;
}
__device__ __forceinline__ unsigned long long pack2f(float lo, float hi) {
    return (unsigned long long)__float_as_uint(lo)
         | ((unsigned long long)__float_as_uint(hi) << 32);
}

// -------- r4-proven grid barrier: monotone counter, cnt spin --------
__device__ __forceinline__ void gridbar(unsigned* cnt, unsigned idx) {
    __syncthreads();
    if (threadIdx.x == 0) {
        __atomic_signal_fence(__ATOMIC_SEQ_CST);
        __builtin_amdgcn_s_waitcnt(0);   // drain this wave's coherent stores
        __hip_atomic_fetch_add(cnt, 1u, __ATOMIC_RELAXED, __HIP_MEMORY_SCOPE_AGENT);
        const unsigned target = idx * (unsigned)NBLK;
        long long g = 0;
        while (__hip_atomic_load(cnt, __ATOMIC_RELAXED, __HIP_MEMORY_SCOPE_AGENT) < target) {
            __builtin_amdgcn_s_sleep(2);
            if (++g > (1LL << 20)) break;   // failsafe: wrong > hung
        }
        __atomic_signal_fence(__ATOMIC_SEQ_CST);
    }
    __syncthreads();
}

__device__ __forceinline__ void apply_rt(float& x, float& y, float& z,
                                         const float* R, const float* T) {
    const float nx = fmaf(x, R[0], fmaf(y, R[3], fmaf(z, R[6], T[0])));
    const float ny = fmaf(x, R[1], fmaf(y, R[4], fmaf(z, R[7], T[1])));
    const float nz = fmaf(x, R[2], fmaf(y, R[5], fmaf(z, R[8], T[2])));
    x = nx; y = ny; z = nz;
}

// ---------------- 3x3 helpers (float, thread-serial) — r4-proven ----------
__device__ float det3f(const float* M) {
    return M[0]*(M[4]*M[8]-M[5]*M[7])
         - M[1]*(M[3]*M[8]-M[5]*M[6])
         + M[2]*(M[3]*M[7]-M[4]*M[6]);
}

__device__ void svd3x3f(const float* A, float* U, float* V, float* sig) {
    float S[9];
    for (int i = 0; i < 3; ++i)
        for (int j = 0; j < 3; ++j) {
            float s = 0.f;
            for (int k = 0; k < 3; ++k) s += A[k*3+i] * A[k*3+j];
            S[i*3+j] = s;
        }
    float Vm[9] = {1,0,0, 0,1,0, 0,0,1};
    for (int sweep = 0; sweep < 20; ++sweep) {
        float off = fabsf(S[1]) + fabsf(S[2]) + fabsf(S[5]);
        float base = fabsf(S[0]) + fabsf(S[4]) + fabsf(S[8]);
        if (off <= 1e-7f * base) break;
        for (int pi = 0; pi < 3; ++pi) {
            const int p = (pi == 2) ? 1 : 0;
            const int q = (pi == 0) ? 1 : 2;
            float apq = S[p*3+q];
            if (apq == 0.f) continue;
            float app = S[p*3+p], aqq = S[q*3+q];
            float tau = (aqq - app) / (2.f * apq);
            float tt  = ((tau >= 0.f) ? 1.f : -1.f) / (fabsf(tau) + sqrtf(1.f + tau*tau));
            float c = 1.f / sqrtf(1.f + tt*tt);
            float s = tt * c;
            for (int k = 0; k < 3; ++k) {
                float skp = S[k*3+p], skq = S[k*3+q];
                S[k*3+p] = c*skp - s*skq;
                S[k*3+q] = s*skp + c*skq;
            }
            for (int k = 0; k < 3; ++k) {
                float spk = S[p*3+k], sqk = S[q*3+k];
                S[p*3+k] = c*spk - s*sqk;
                S[q*3+k] = s*spk + c*sqk;
            }
            for (int k = 0; k < 3; ++k) {
                float vkp = Vm[k*3+p], vkq = Vm[k*3+q];
                Vm[k*3+p] = c*vkp - s*vkq;
                Vm[k*3+q] = s*vkp + c*vkq;
            }
        }
    }
    float lam[3] = {S[0], S[4], S[8]};
    int ord[3] = {0, 1, 2};
    for (int i = 0; i < 2; ++i)
        for (int j = i+1; j < 3; ++j)
            if (lam[ord[j]] > lam[ord[i]]) { int tmp = ord[i]; ord[i] = ord[j]; ord[j] = tmp; }
    for (int i = 0; i < 3; ++i) {
        int o = ord[i];
        float l = lam[o] > 0.f ? lam[o] : 0.f;
        sig[i] = sqrtf(l);
        for (int k = 0; k < 3; ++k) V[k*3+i] = Vm[k*3+o];
    }
    for (int i = 0; i < 3; ++i) {
        float u0 = 0, u1 = 0, u2 = 0;
        for (int k = 0; k < 3; ++k) {
            u0 += A[0*3+k] * V[k*3+i];
            u1 += A[1*3+k] * V[k*3+i];
            u2 += A[2*3+k] * V[k*3+i];
        }
        float nrm = sqrtf(u0*u0 + u1*u1 + u2*u2);
        if (nrm > 1e-30f) { u0 /= nrm; u1 /= nrm; u2 /= nrm; }
        else {
            float ax = U[0], ay = U[3], az = U[6];
            float bx = U[1], by = U[4], bz = U[7];
            u0 = ay*bz - az*by; u1 = az*bx - ax*bz; u2 = ax*by - ay*bx;
        }
        U[0*3+i] = u0; U[1*3+i] = u1; U[2*3+i] = u2;
    }
}

// u,s,vT = svd(H); v=vT^T; d=det(v@u^T); v[2,2]*=d; R = v' @ u^T;
// t[j] = p2c[j] - sum_k p1c[k]*R[k][j]
__device__ void compute_Rt(const float* H, const float* p1c, const float* p2c,
                           float* Rout, float* tout) {
    float U[9], V[9], sig[3];
    svd3x3f(H, U, V, sig);
    float d = (det3f(U) * det3f(V) < 0.f) ? -1.f : 1.f;
    V[2*3+2] *= d;
    float R[9];
    for (int i = 0; i < 3; ++i)
        for (int j = 0; j < 3; ++j) {
            float s = 0.f;
            for (int k = 0; k < 3; ++k) s += V[i*3+k] * U[j*3+k];
            R[i*3+j] = s;
        }
    for (int j = 0; j < 3; ++j) {
        float s = 0.f;
        for (int k = 0; k < 3; ++k) s += p1c[k] * R[k*3+j];
        tout[j] = p2c[j] - s;
    }
    for (int k = 0; k < 9; ++k) Rout[k] = R[k];
}

__device__ inline float wred(float v) {
    v += __shfl_down(v, 32);
    v += __shfl_down(v, 16);
    v += __shfl_down(v, 8);
    v += __shfl_down(v, 4);
    v += __shfl_down(v, 2);
    v += __shfl_down(v, 1);
    return v;   // valid on lane 0 of each wave
}

// ---------------- the single kernel ----------------
__global__ void __launch_bounds__(NT) k_icp(const float* __restrict__ p1,
                                            const float* __restrict__ p2,
                                            float* __restrict__ out,
                                            float* __restrict__ tempf,
                                            unsigned long long* __restrict__ nn,
                                            unsigned* __restrict__ cnt,
                                            int* __restrict__ done_flag) {
    const int t = threadIdx.x, blk = blockIdx.x;
    const int nb = blk >> 5;              // NN batch
    const int qb = (blk & 31) * 64;       // NN query base (64 queries/block)
    unsigned long long* temp64 = (unsigned long long*)tempf;

    __shared__ alignas(16) float scf[N*3];        // 24 KB: whole-batch candidates
    unsigned long long* sl64 = (unsigned long long*)scf;
    __shared__ unsigned long long part[4][64];
    __shared__ int   sIdx[N];                     // 8 KB
    __shared__ float lred[4][9];
    __shared__ float sRT[12], sc1v[3], sc2v[3];
    __shared__ float lds4w[4];
    __shared__ int sdone;

    unsigned baridx = 0;
    float prev_err = 0.f;   // live in blk 4, t 0

    for (int it = 0; it < MAXIT; ++it) {
        if (t == 0) sdone = __hip_atomic_load(done_flag, __ATOMIC_RELAXED, __HIP_MEMORY_SCOPE_AGENT);
        __syncthreads();
        if (sdone) break;

        // ---- stage this batch's full candidate cloud into LDS ----
        if (it == 0) {
            const unsigned long long* src = ((const unsigned long long*)p1) + nb*3072;
            for (int u = t; u < 3072; u += NT) sl64[u] = src[u];       // plain cached
        } else {
            const unsigned long long* src = temp64 + nb*3072;
            for (int u = t; u < 3072; u += NT) sl64[u] = cohld64(&src[u]);
        }
        __syncthreads();

        // ---- NN: lane = query, wave = candidate quarter ----
        {
            const int lane = t & 63, w = t >> 6;
            const float* qp = &p2[(nb*N + qb + lane)*3];
            const float px = qp[0], py = qp[1], pz = qp[2];
            float bestd = __uint_as_float(0x7f7fffffu);   // FLT_MAX
            int   besti = 0;
            const int c0 = w * 512;
            #pragma unroll 4
            for (int j = 0; j < 512; ++j) {
                const int c = c0 + j;                      // wave-uniform -> LDS broadcast
                const float dx = px - scf[c*3+0];
                const float dy = py - scf[c*3+1];
                const float dz = pz - scf[c*3+2];
                const float d2 = fmaf(dx, dx, fmaf(dy, dy, dz*dz));
                if (d2 < bestd) { bestd = d2; besti = c; } // strict < keeps lowest idx
            }
            part[w][lane] = ((unsigned long long)__float_as_uint(bestd) << 32) | (unsigned)besti;
        }
        __syncthreads();
        if (t < 64) {
            unsigned long long m = part[0][t];
            m = umin64(m, part[1][t]);
            m = umin64(m, part[2][t]);
            m = umin64(m, part[3][t]);
            cohst64(&nn[nb*N + qb + t], m);   // single plain coherent store per query
        }
        gridbar(cnt, ++baridx);

        // ---- reduce: blocks 0..3 per-batch transform, block 4 mean-err ----
        if (blk < 4) {
            const int b = blk;
            // batch-3 nn row (reference's idx[-1] quirk)
            for (int i = t; i < N; i += NT)
                sIdx[i] = (int)(unsigned)(cohld64(&nn[3*N + i]) & 0xffffffffULL);
            __syncthreads();
            const int wave = t >> 6, lane = t & 63;

            // phase A: centroids of temp[b] and matched (p2[b] gathered)
            float v6[6] = {0,0,0,0,0,0};
            for (int i = t; i < N; i += NT) {
                float x1, y1, z1;
                if (it == 0) {
                    const float* pp = &p1[(b*N+i)*3];
                    x1 = pp[0]; y1 = pp[1]; z1 = pp[2];
                } else {
                    const float* tp = &tempf[(b*N+i)*3];
                    x1 = cohldf(tp); y1 = cohldf(tp+1); z1 = cohldf(tp+2);
                }
                v6[0] += x1; v6[1] += y1; v6[2] += z1;
                const int mi = sIdx[i];
                const float* mp = &p2[(b*N+mi)*3];
                v6[3] += mp[0]; v6[4] += mp[1]; v6[5] += mp[2];
            }
            #pragma unroll
            for (int k = 0; k < 6; ++k) v6[k] = wred(v6[k]);
            if (lane == 0) {
                #pragma unroll
                for (int k = 0; k < 6; ++k) lred[wave][k] = v6[k];
            }
            __syncthreads();
            if (t == 0) {
                #pragma unroll
                for (int k = 0; k < 3; ++k) {
                    sc1v[k] = (lred[0][k]  +lred[1][k]  +lred[2][k]  +lred[3][k])   / (float)N;
                    sc2v[k] = (lred[0][3+k]+lred[1][3+k]+lred[2][3+k]+lred[3][3+k]) / (float)N;
                }
            }
            __syncthreads();
            const float c1x = sc1v[0], c1y = sc1v[1], c1z = sc1v[2];
            const float c2x = sc2v[0], c2y = sc2v[1], c2z = sc2v[2];

            // phase B: H[j][k] = sum (matched - c2)_j * (temp - c1)_k
            float h[9];
            #pragma unroll
            for (int k = 0; k < 9; ++k) h[k] = 0.f;
            for (int i = t; i < N; i += NT) {
                float x1, y1, z1;
                if (it == 0) {
                    const float* pp = &p1[(b*N+i)*3];
                    x1 = pp[0]; y1 = pp[1]; z1 = pp[2];
                } else {
                    const float* tp = &tempf[(b*N+i)*3];
                    x1 = cohldf(tp); y1 = cohldf(tp+1); z1 = cohldf(tp+2);
                }
                const int mi = sIdx[i];
                const float* mp = &p2[(b*N+mi)*3];
                const float bx = x1-c1x, by = y1-c1y, bz = z1-c1z;     // q1
                const float ax = mp[0]-c2x, ay = mp[1]-c2y, az = mp[2]-c2z; // q2
                h[0] += ax*bx; h[1] += ax*by; h[2] += ax*bz;
                h[3] += ay*bx; h[4] += ay*by; h[5] += ay*bz;
                h[6] += az*bx; h[7] += az*by; h[8] += az*bz;
            }
            #pragma unroll
            for (int k = 0; k < 9; ++k) h[k] = wred(h[k]);
            if (lane == 0) {
                #pragma unroll
                for (int k = 0; k < 9; ++k) lred[wave][k] = h[k];
            }
            __syncthreads();
            if (t == 0) {
                float H[9], c1d[3], c2d[3];
                for (int k = 0; k < 9; ++k)
                    H[k] = lred[0][k]+lred[1][k]+lred[2][k]+lred[3][k];
                c1d[0]=c1x; c1d[1]=c1y; c1d[2]=c1z;
                c2d[0]=c2x; c2d[1]=c2y; c2d[2]=c2z;
                compute_Rt(H, c1d, c2d, sRT, sRT + 9);
            }
            __syncthreads();
            // apply R,t; write temp as packed u64 pairs (2 points -> 3 stores)
            #pragma unroll
            for (int j = 0; j < 4; ++j) {
                const int p = 2*(t + 256*j);
                float x0,y0,z0, x1,y1,z1;
                if (it == 0) {
                    const float* a = &p1[(b*N+p)*3];
                    x0=a[0]; y0=a[1]; z0=a[2]; x1=a[3]; y1=a[4]; z1=a[5];
                } else {
                    const float* a = &tempf[(b*N+p)*3];
                    x0=cohldf(a);   y0=cohldf(a+1); z0=cohldf(a+2);
                    x1=cohldf(a+3); y1=cohldf(a+4); z1=cohldf(a+5);
                }
                apply_rt(x0,y0,z0, sRT, sRT+9);
                apply_rt(x1,y1,z1, sRT, sRT+9);
                const int ub = b*3072 + 3*(t + 256*j);
                cohst64(&temp64[ub+0], pack2f(x0, y0));
                cohst64(&temp64[ub+1], pack2f(z0, x1));
                cohst64(&temp64[ub+2], pack2f(y1, z1));
            }
        } else if (blk == 4) {
            // mean err over all batches (no reset needed — nn fully rewritten)
            float s = 0.f;
            for (int i = t; i < B*N; i += NT)
                s += sqrtf(__uint_as_float((unsigned)(cohld64(&nn[i]) >> 32)));
            s = wred(s);
            if ((t & 63) == 0) lds4w[t >> 6] = s;
            __syncthreads();
            if (t == 0) {
                const float me = (lds4w[0]+lds4w[1]+lds4w[2]+lds4w[3]) / (float)(B*N);
                __hip_atomic_store(done_flag, (fabsf(prev_err - me) < TOL) ? 1 : 0,
                                   __ATOMIC_RELAXED, __HIP_MEMORY_SCOPE_AGENT);
                prev_err = me;
            }
        }
        gridbar(cnt, ++baridx);
    }

    // ---- final: T = get_transform(p1, temp) ----
    if (blk < 4) {
        const int b = blk;
        const int wave = t >> 6, lane = t & 63;
        float v6[6] = {0,0,0,0,0,0};
        for (int i = t; i < N; i += NT) {
            const float* pp = &p1[(b*N+i)*3];
            const float* tp = &tempf[(b*N+i)*3];
            v6[0] += pp[0]; v6[1] += pp[1]; v6[2] += pp[2];
            v6[3] += cohldf(tp); v6[4] += cohldf(tp+1); v6[5] += cohldf(tp+2);
        }
        #pragma unroll
        for (int k = 0; k < 6; ++k) v6[k] = wred(v6[k]);
        if (lane == 0) {
            #pragma unroll
            for (int k = 0; k < 6; ++k) lred[wave][k] = v6[k];
        }
        __syncthreads();
        if (t == 0) {
            #pragma unroll
            for (int k = 0; k < 3; ++k) {
                sc1v[k] = (lred[0][k]  +lred[1][k]  +lred[2][k]  +lred[3][k])   / (float)N;
                sc2v[k] = (lred[0][3+k]+lred[1][3+k]+lred[2][3+k]+lred[3][3+k]) / (float)N;
            }
        }
        __syncthreads();
        const float c1x = sc1v[0], c1y = sc1v[1], c1z = sc1v[2];
        const float c2x = sc2v[0], c2y = sc2v[1], c2z = sc2v[2];

        float h[9];
        #pragma unroll
        for (int k = 0; k < 9; ++k) h[k] = 0.f;
        for (int i = t; i < N; i += NT) {
            const float* pp = &p1[(b*N+i)*3];
            const float* tp = &tempf[(b*N+i)*3];
            const float bx = pp[0]-c1x, by = pp[1]-c1y, bz = pp[2]-c1z;           // q1
            const float ax = cohldf(tp)-c2x, ay = cohldf(tp+1)-c2y, az = cohldf(tp+2)-c2z; // q2
            h[0] += ax*bx; h[1] += ax*by; h[2] += ax*bz;
            h[3] += ay*bx; h[4] += ay*by; h[5] += ay*bz;
            h[6] += az*bx; h[7] += az*by; h[8] += az*bz;
        }
        #pragma unroll
        for (int k = 0; k < 9; ++k) h[k] = wred(h[k]);
        if (lane == 0) {
            #pragma unroll
            for (int k = 0; k < 9; ++k) lred[wave][k] = h[k];
        }
        __syncthreads();
        if (t == 0) {
            float H[9], c1d[3], c2d[3], Rf[9], Tf[3];
            for (int k = 0; k < 9; ++k)
                H[k] = lred[0][k]+lred[1][k]+lred[2][k]+lred[3][k];
            c1d[0]=c1x; c1d[1]=c1y; c1d[2]=c1z;
            c2d[0]=c2x; c2d[1]=c2y; c2d[2]=c2z;
            compute_Rt(H, c1d, c2d, Rf, Tf);
            for (int i = 0; i < 3; ++i) {
                out[b*12 + i*4 + 0] = Rf[i*3+0];
                out[b*12 + i*4 + 1] = Rf[i*3+1];
                out[b*12 + i*4 + 2] = Rf[i*3+2];
                out[b*12 + i*4 + 3] = Tf[i];
            }
        }
    }
}

extern "C" void kernel_launch(void* const* d_in, const int* in_sizes, int n_in,
                              void* d_out, int out_size, void* d_ws, size_t ws_size,
                              hipStream_t stream) {
    const float* p1 = (const float*)d_in[0];
    const float* p2 = (const float*)d_in[1];
    float* out = (float*)d_out;
    float* tempf = (float*)d_ws;
    unsigned long long* nn = (unsigned long long*)((char*)d_ws + 98304);
    unsigned* cnt  = (unsigned*)((char*)d_ws + 163840);
    int*      done = (int*)((char*)d_ws + 163904);

    // zero cnt/done (ws re-poisoned 0xAA before every timed launch)
    hipMemsetAsync((char*)d_ws + 163840, 0, 512, stream);

    void* args[] = { (void*)&p1, (void*)&p2, (void*)&out, (void*)&tempf,
                     (void*)&nn, (void*)&cnt, (void*)&done };
    hipLaunchCooperativeKernel((const void*)k_icp, dim3(NBLK), dim3(NT),
                               args, 0, stream);
}